// Round 6
// baseline (6372.610 us; speedup 1.0000x reference)
//
#include <hip/hip_runtime.h>
#include <math.h>

namespace {

constexpr int Bn = 4;
constexpr int H0 = 256, W0 = 448;
constexpr int H1 = 128, W1 = 224;
constexpr int H2 = 64,  W2 = 112;
constexpr int TPB = 256;

// np.linspace(-1+1/n, 1-1/n, n, dtype=float32): computed in f64, endpoint
// forced, cast to f32. (Used only in the gather-side backwarp, where ulp
// differences are harmless — validated by level-0 pass.)
__device__ inline float lin_ac_f32(int i, int n) {
    if (i == n - 1) return (float)(1.0 - 1.0 / (double)n);
    double start = -1.0 + 1.0 / (double)n;
    double step  = (2.0 - 2.0 / (double)n) / (double)(n - 1);
    return (float)(start + (double)i * step);
}

// ---------------------------------------------------------------------------
// Backwarp + L1 occlusion metric (validated: level 0 passes). Unchanged.
// ---------------------------------------------------------------------------
__global__ void metric_kernel(const float* __restrict__ imgA,
                              const float* __restrict__ imgB,
                              const float* __restrict__ flow,
                              float* __restrict__ mout) {
    int idx = blockIdx.x * blockDim.x + threadIdx.x;
    int total = Bn * H0 * W0;
    if (idx >= total) return;
    int x = idx % W0;
    int y = (idx / W0) % H0;
    int b = idx / (W0 * H0);

    const float* fb = flow + (size_t)b * 2 * H0 * W0;
    float fx = fb[y * W0 + x];
    float fy = fb[(size_t)H0 * W0 + y * W0 + x];

    const float sxc = (float)(2.0 / (double)(W0 - 1));
    const float syc = (float)(2.0 / (double)(H0 - 1));
    float gx = __fadd_rn(lin_ac_f32(x, W0), __fmul_rn(fx, sxc));
    float gy = __fadd_rn(lin_ac_f32(y, H0), __fmul_rn(fy, syc));
    float px = __fmul_rn(__fmul_rn(__fadd_rn(gx, 1.0f), 0.5f), (float)(W0 - 1));
    float py = __fmul_rn(__fmul_rn(__fadd_rn(gy, 1.0f), 0.5f), (float)(H0 - 1));

    float x0f = floorf(px), y0f = floorf(py);
    float x1f = x0f + 1.0f, y1f = y0f + 1.0f;
    int x0 = (int)x0f, y0 = (int)y0f, x1 = (int)x1f, y1 = (int)y1f;

    float tw[4] = { (x1f - px) * (y1f - py), (px - x0f) * (y1f - py),
                    (x1f - px) * (py - y0f), (px - x0f) * (py - y0f) };
    int tx[4] = { x0, x1, x0, x1 };
    int ty[4] = { y0, y0, y1, y1 };

    const float* ib = imgB + (size_t)b * 3 * H0 * W0;
    float acc0 = 0.f, acc1 = 0.f, acc2 = 0.f;
#pragma unroll
    for (int t = 0; t < 4; ++t) {
        bool valid = (tx[t] >= 0) && (tx[t] < W0) && (ty[t] >= 0) && (ty[t] < H0);
        int xc = min(max(tx[t], 0), W0 - 1);
        int yc = min(max(ty[t], 0), H0 - 1);
        float ww = valid ? tw[t] : 0.f;
        int off = yc * W0 + xc;
        acc0 += ib[off] * ww;
        acc1 += ib[(size_t)H0 * W0 + off] * ww;
        acc2 += ib[(size_t)2 * H0 * W0 + off] * ww;
    }
    const float* ia = imgA + (size_t)b * 3 * H0 * W0;
    int off = y * W0 + x;
    float m = (fabsf(ia[off] - acc0) +
               fabsf(ia[(size_t)H0 * W0 + off] - acc1) +
               fabsf(ia[(size_t)2 * H0 * W0 + off] - acc2)) * (1.f / 3.f);
    mout[idx] = m;
}

// ---------------------------------------------------------------------------
// jax-f32 linspace bit path: v = round32(delta_f32 * i), delta precomputed
// on host as (float)(n_in-1)/(float)(n_out-1)  [validated: 2.73 -> 0.156
// collapse in round 4], PLUS jax's endpoint forcing: linspace(endpoint=True)
// concatenates the exact `stop` as the last element, so i == n_out-1 yields
// exactly n_in-1 (fl(delta*(n_out-1)) != n_in-1 for the x axes here!).
// ---------------------------------------------------------------------------
__device__ inline void ac32_iota(int i, int n_in, int n_out, float delta,
                                 int& i0, int& i1, float& fr) {
    float v = (i == n_out - 1) ? (float)(n_in - 1) : __fmul_rn(delta, (float)i);
    float f0 = floorf(v);
    i0 = (int)f0;
    i1 = min(i0 + 1, n_in - 1);
    fr = __fsub_rn(v, f0);
}

// Unfused f32 bilinear, pinned so hipcc cannot contract to FMA (round-4
// branch: 0.156 < round-5 fused 0.1875 -> reference blend is unfused).
// Matches: rows = a*(1-wy) + b*wy ; out = r0*(1-wx) + r1*wx.
__device__ inline float bilerp32(const float* __restrict__ s, int Win,
                                 int y0, int y1, int x0, int x1,
                                 float wy, float wx) {
    float a = s[y0 * Win + x0], b = s[y1 * Win + x0];
    float c = s[y0 * Win + x1], d = s[y1 * Win + x1];
    float omwy = __fsub_rn(1.0f, wy), omwx = __fsub_rn(1.0f, wx);
    float r0 = __fadd_rn(__fmul_rn(a, omwy), __fmul_rn(b, wy));
    float r1 = __fadd_rn(__fmul_rn(c, omwy), __fmul_rn(d, wy));
    return __fadd_rn(__fmul_rn(r0, omwx), __fmul_rn(r1, wx));
}

// ---------------------------------------------------------------------------
// Level-0 softmax-splat (validated: passes). Unchanged.
// ---------------------------------------------------------------------------
__global__ void splat0_kernel(const float* __restrict__ srcA, int CA,
                              const float* __restrict__ srcB, int CB,
                              const float* __restrict__ flowFull,
                              const float* __restrict__ metric,
                              const float* __restrict__ alpha,
                              float* __restrict__ out, int Cout, int cbase,
                              float* __restrict__ wacc) {
    int idx = blockIdx.x * blockDim.x + threadIdx.x;
    int total = Bn * H0 * W0;
    if (idx >= total) return;
    const int h = H0, w = W0;
    int x = idx % w;
    int y = (idx / w) % h;
    int b = idx / (w * h);

    const float* fb = flowFull + (size_t)b * 2 * H0 * W0;
    float fx = 0.5f * fb[y * W0 + x];
    float fy = 0.5f * fb[(size_t)H0 * W0 + y * W0 + x];

    float wgt = expf(alpha[0] * metric[idx]);

    float gx = (float)x + fx;
    float gy = (float)y + fy;
    float x0f = floorf(gx), y0f = floorf(gy);
    float x1f = x0f + 1.f,  y1f = y0f + 1.f;
    int x0 = (int)x0f, y0 = (int)y0f, x1 = (int)x1f, y1 = (int)y1f;

    float twv[4] = { (x1f - gx) * (y1f - gy) * wgt, (gx - x0f) * (y1f - gy) * wgt,
                     (x1f - gx) * (gy - y0f) * wgt, (gx - x0f) * (gy - y0f) * wgt };
    int tx[4] = { x0, x1, x0, x1 };
    int ty[4] = { y0, y0, y1, y1 };
    int tidx[4];
#pragma unroll
    for (int t = 0; t < 4; ++t) {
        bool valid = (tx[t] >= 0) && (tx[t] < w) && (ty[t] >= 0) && (ty[t] < h);
        tidx[t] = valid ? (ty[t] * w + tx[t]) : -1;
    }

    float* wb = wacc + (size_t)b * h * w;
#pragma unroll
    for (int t = 0; t < 4; ++t)
        if (tidx[t] >= 0) atomicAdd(wb + tidx[t], twv[t]);

    int src_off = y * w + x;
    float* ob = out + ((size_t)b * Cout + cbase) * h * w;
    int Ctot = CA + CB;
    for (int c = 0; c < Ctot; ++c) {
        const float* sp = (c < CA)
            ? (srcA + ((size_t)b * CA + c) * h * w)
            : (srcB + ((size_t)b * CB + (c - CA)) * h * w);
        float v = sp[src_off];
        float* op = ob + (size_t)c * h * w;
#pragma unroll
        for (int t = 0; t < 4; ++t)
            if (tidx[t] >= 0) atomicAdd(op + tidx[t], v * twv[t]);
    }
}

// ---------------------------------------------------------------------------
// Level-1/2 softmax-splat with fused f32 resize (flow + metric). Level scale
// (0.25 / 0.125) is pow2: exact, commutes bitwise with the reference's
// pre-scaled resize (pow2 scaling commutes exactly through mul/add).
// ---------------------------------------------------------------------------
__global__ void splatL_kernel(const float* __restrict__ srcB, int CB,
                              const float* __restrict__ rawFlow,
                              const float* __restrict__ rawMet,
                              const float* __restrict__ alpha, float scale,
                              float dy, float dx,
                              float* __restrict__ out, int Cout, int cbase,
                              float* __restrict__ wacc, int h, int w) {
    int idx = blockIdx.x * blockDim.x + threadIdx.x;
    int total = Bn * h * w;
    if (idx >= total) return;
    int x = idx % w;
    int y = (idx / w) % h;
    int b = idx / (w * h);

    int ry0, ry1, rx0, rx1; float wy, wx;
    ac32_iota(y, H0, h, dy, ry0, ry1, wy);
    ac32_iota(x, W0, w, dx, rx0, rx1, wx);

    const float* mB = rawMet + (size_t)b * H0 * W0;
    float m = bilerp32(mB, W0, ry0, ry1, rx0, rx1, wy, wx);

    const float* fB = rawFlow + (size_t)b * 2 * H0 * W0;
    float fx = __fmul_rn(bilerp32(fB, W0, ry0, ry1, rx0, rx1, wy, wx), scale);
    float fy = __fmul_rn(bilerp32(fB + (size_t)H0 * W0, W0, ry0, ry1, rx0, rx1, wy, wx), scale);

    float wgt = expf(__fmul_rn(alpha[0], m));

    float gx = __fadd_rn((float)x, fx);
    float gy = __fadd_rn((float)y, fy);
    float x0f = floorf(gx), y0f = floorf(gy);
    float x1f = __fadd_rn(x0f, 1.0f), y1f = __fadd_rn(y0f, 1.0f);

    float dx0 = __fsub_rn(x1f, gx), dx1 = __fsub_rn(gx, x0f);
    float dy0 = __fsub_rn(y1f, gy), dy1 = __fsub_rn(gy, y0f);
    float tw[4] = { __fmul_rn(dx0, dy0), __fmul_rn(dx1, dy0),
                    __fmul_rn(dx0, dy1), __fmul_rn(dx1, dy1) };
    int tx[4] = { (int)x0f, (int)x1f, (int)x0f, (int)x1f };
    int ty[4] = { (int)y0f, (int)y0f, (int)y1f, (int)y1f };
    int tidx[4];
#pragma unroll
    for (int t = 0; t < 4; ++t) {
        bool valid = (tx[t] >= 0) && (tx[t] < w) && (ty[t] >= 0) && (ty[t] < h);
        tidx[t] = valid ? (ty[t] * w + tx[t]) : -1;
    }

    float* wb = wacc + (size_t)b * h * w;
#pragma unroll
    for (int t = 0; t < 4; ++t)
        if (tidx[t] >= 0) atomicAdd(wb + tidx[t], __fmul_rn(wgt, tw[t]));

    int src_off = y * w + x;
    float* ob = out + ((size_t)b * Cout + cbase) * h * w;
    for (int c = 0; c < CB; ++c) {
        float v = srcB[((size_t)b * CB + c) * h * w + src_off];
        float vw = __fmul_rn(v, wgt);   // ref: vals = x*wgt, then *tap
        float* op = ob + (size_t)c * h * w;
#pragma unroll
        for (int t = 0; t < 4; ++t)
            if (tidx[t] >= 0) atomicAdd(op + tidx[t], __fmul_rn(vw, tw[t]));
    }
}

__global__ void norm_kernel(float* __restrict__ out,
                            const float* __restrict__ wacc1,
                            const float* __restrict__ wacc2,
                            int Cout, int split, int h, int w) {
    int idx = blockIdx.x * blockDim.x + threadIdx.x;
    long long total = (long long)Bn * Cout * h * w;
    if (idx >= total) return;
    int hw = h * w;
    int pix = idx % hw;
    int c = (idx / hw) % Cout;
    int b = idx / (hw * Cout);
    const float* wa = (c < split) ? wacc1 : wacc2;
    float d = wa[(size_t)b * hw + pix] + 1e-7f;
    out[idx] /= d;
}

inline int nblk(long long n) { return (int)((n + TPB - 1) / TPB); }

} // namespace

extern "C" void kernel_launch(void* const* d_in, const int* in_sizes, int n_in,
                              void* d_out, int out_size, void* d_ws, size_t ws_size,
                              hipStream_t stream) {
    const float* img1 = (const float*)d_in[0];
    const float* img2 = (const float*)d_in[1];
    const float* f1_1 = (const float*)d_in[2];
    const float* f1_2 = (const float*)d_in[3];
    const float* f1_3 = (const float*)d_in[4];
    const float* f2_1 = (const float*)d_in[5];
    const float* f2_2 = (const float*)d_in[6];
    const float* f2_3 = (const float*)d_in[7];
    const float* fl12 = (const float*)d_in[8];
    const float* fl21 = (const float*)d_in[9];
    const float* alpha = (const float*)d_in[10];
    float* out = (float*)d_out;

    // jax-f32 linspace deltas, host IEEE f32 division
    const float dy1 = (float)(H0 - 1) / (float)(H1 - 1);
    const float dx1 = (float)(W0 - 1) / (float)(W1 - 1);
    const float dy2 = (float)(H0 - 1) / (float)(H2 - 1);
    const float dx2 = (float)(W0 - 1) / (float)(W2 - 1);

    // ---- workspace (all f32): metrics + weight planes; ~8.5 MB ----
    float* ws = (float*)d_ws;
    size_t o = 0;
    float* m12   = ws + o; o += (size_t)Bn * H0 * W0;
    float* m21   = ws + o; o += (size_t)Bn * H0 * W0;
    float* wacc  = ws + o;                 // start of zeroed region
    float* w1_l0 = ws + o; o += (size_t)Bn * H0 * W0;
    float* w2_l0 = ws + o; o += (size_t)Bn * H0 * W0;
    float* w1_l1 = ws + o; o += (size_t)Bn * H1 * W1;
    float* w2_l1 = ws + o; o += (size_t)Bn * H1 * W1;
    float* w1_l2 = ws + o; o += (size_t)Bn * H2 * W2;
    float* w2_l2 = ws + o; o += (size_t)Bn * H2 * W2;
    size_t wacc_bytes = (size_t)(w2_l2 + (size_t)Bn * H2 * W2 - wacc) * sizeof(float);

    float* l1 = out;                                        // (B,70,H0,W0)
    float* l2 = l1 + (size_t)Bn * 70 * H0 * W0;             // (B,128,H1,W1)
    float* l3 = l2 + (size_t)Bn * 128 * H1 * W1;            // (B,192,H2,W2)

    hipMemsetAsync(d_out, 0, (size_t)out_size * sizeof(float), stream);
    hipMemsetAsync(wacc, 0, wacc_bytes, stream);

    // ---- metrics ----
    long long npx0 = (long long)Bn * H0 * W0;
    metric_kernel<<<nblk(npx0), TPB, 0, stream>>>(img1, img2, fl12, m12);
    metric_kernel<<<nblk(npx0), TPB, 0, stream>>>(img2, img1, fl21, m21);

    // ---- splats (resize fused into level-1/2 kernels) ----
    long long npx1 = (long long)Bn * H1 * W1;
    long long npx2 = (long long)Bn * H2 * W2;
    splat0_kernel<<<nblk(npx0), TPB, 0, stream>>>(img1, 3, f1_1, 32, fl12,
                                                  m12, alpha, l1, 70, 0,  w1_l0);
    splat0_kernel<<<nblk(npx0), TPB, 0, stream>>>(img2, 3, f2_1, 32, fl21,
                                                  m21, alpha, l1, 70, 35, w2_l0);
    splatL_kernel<<<nblk(npx1), TPB, 0, stream>>>(f1_2, 64, fl12, m12, alpha, 0.25f,
                                                  dy1, dx1, l2, 128, 0,  w1_l1, H1, W1);
    splatL_kernel<<<nblk(npx1), TPB, 0, stream>>>(f2_2, 64, fl21, m21, alpha, 0.25f,
                                                  dy1, dx1, l2, 128, 64, w2_l1, H1, W1);
    splatL_kernel<<<nblk(npx2), TPB, 0, stream>>>(f1_3, 96, fl12, m12, alpha, 0.125f,
                                                  dy2, dx2, l3, 192, 0,  w1_l2, H2, W2);
    splatL_kernel<<<nblk(npx2), TPB, 0, stream>>>(f2_3, 96, fl21, m21, alpha, 0.125f,
                                                  dy2, dx2, l3, 192, 96, w2_l2, H2, W2);

    // ---- normalize ----
    long long no1 = (long long)Bn * 70 * H0 * W0;
    long long no2 = (long long)Bn * 128 * H1 * W1;
    long long no3 = (long long)Bn * 192 * H2 * W2;
    norm_kernel<<<nblk(no1), TPB, 0, stream>>>(l1, w1_l0, w2_l0, 70, 35, H0, W0);
    norm_kernel<<<nblk(no2), TPB, 0, stream>>>(l2, w1_l1, w2_l1, 128, 64, H1, W1);
    norm_kernel<<<nblk(no3), TPB, 0, stream>>>(l3, w1_l2, w2_l2, 192, 96, H2, W2);
}